// Round 13
// baseline (35.239 us; speedup 1.0000x reference)
//
#include <hip/hip_runtime.h>
#include <hip/hip_bf16.h>

typedef __attribute__((ext_vector_type(8))) short short8v;
typedef __attribute__((ext_vector_type(4))) float float4v;

// Problem constants
#define NB 64
#define NN 2048
#define ED 128
#define GRID_P 2048           // 1-wave blocks, 64 pairs each (4 chunks of 16)

// workspace layout (float offsets)
#define WS_WEFF  0                  // 64 (weff[63], [63]=0)
#define WS_BEFF  64                 // 1
#define WS_SHIGH 128                // 64
#define WS_QTERM 192                // 64*64  (qterm + b3 folded)
#define WS_QPRE  (192+4096)         // 64*128
#define WS_BPACK (192+4096+8192)    // bf16[16384] = 4096 floats, 16B aligned

static __device__ __forceinline__ unsigned int packbf2(float a, float b) {
    __hip_bfloat162 h = __float22bfloat162_rn(make_float2(a, b));
    return *(unsigned int*)&h;
}

// ---------------- Kernel P (unchanged from r12) ----------------
__global__ __launch_bounds__(64) void k_prep(
    const float* __restrict__ top_user, const float* __restrict__ question,
    const float* __restrict__ W1, const float* __restrict__ b1,
    const float* __restrict__ W2, const float* __restrict__ b2,
    const float* __restrict__ W3, const float* __restrict__ b3,
    const float* __restrict__ fw1, const float* __restrict__ fb1,
    const float* __restrict__ fw2, const float* __restrict__ fb2,
    const float* __restrict__ fw3, const float* __restrict__ fb3,
    float* __restrict__ ws, float* __restrict__ out)
{
    const int lane = threadIdx.x;
    const int blk = blockIdx.x;
    __shared__ float g[16];
    __shared__ float w3s[192];
    w3s[lane] = W3[lane];
    w3s[64 + lane] = W3[64 + lane];
    w3s[128 + lane] = W3[128 + lane];
    if (lane < 16) {
        float s = 0.f;
        #pragma unroll
        for (int i = 0; i < 16; ++i) s += fw3[i] * fw2[i*16 + lane];
        g[lane] = s;
    }
    __syncthreads();

    if (blk >= NB) {
        const int kt = blk - NB;
        if (kt == 0) {
            if (lane == 0) out[0] = 0.f;
            float wv = 0.f;
            if (lane < 63) {
                #pragma unroll
                for (int k = 0; k < 16; ++k) wv += g[k] * fw1[k*63 + lane];
            }
            ws[WS_WEFF + lane] = wv;
            if (lane == 0) {
                float be = fb3[0];
                #pragma unroll
                for (int i = 0; i < 16; ++i) be += fw3[i] * fb2[i];
                #pragma unroll
                for (int k = 0; k < 16; ++k) be += g[k] * fb1[k];
                ws[WS_BEFF] = be;
            }
        }
        __hip_bfloat16* bp = (__hip_bfloat16*)(ws + WS_BPACK);
        const int g8 = (lane >> 4) * 8, li = lane & 15;
        #pragma unroll
        for (int nt = 0; nt < 4; ++nt) {
            const int tt = nt*16 + li;
            #pragma unroll
            for (int idx = 0; idx < 8; ++idx) {
                const int k = kt*32 + g8 + idx;
                const int j = k - tt;
                const int k2 = k - 128, j2 = k2 - tt;
                const bool v0 = (tt < 63) && (k < 126) && (j >= 0) && (j < 64);
                const bool v2 = (tt < 63) && (k2 >= 0) && (k2 < 126) && (j2 >= 0) && (j2 < 64);
                float v = (v0 ? w3s[j & 63] : 0.f) + (v2 ? w3s[128 + (j2 & 63)] : 0.f);
                bp[((kt*4 + nt)*64 + lane)*8 + idx] = __float2bfloat16(v);
            }
        }
        return;
    }

    float wv = 0.f;
    if (lane < 63) {
        #pragma unroll
        for (int k = 0; k < 16; ++k) wv += g[k] * fw1[k*63 + lane];
    }
    float be = fb3[0];
    #pragma unroll
    for (int i = 0; i < 16; ++i) be += fw3[i] * fb2[i];
    #pragma unroll
    for (int k = 0; k < 16; ++k) be += g[k] * fb1[k];

    __shared__ float q[132], tu[132], c1q[128], qt[64];
    __shared__ float4 D4[64];
    const int b = blk;
    ((float2*)q)[lane]  = ((const float2*)(question + b*ED))[lane];
    ((float2*)tu)[lane] = ((const float2*)(top_user + b*ED))[lane];
    if (lane == 63) {
        q[128]=0.f; q[129]=0.f; q[130]=0.f; q[131]=0.f;
        tu[128]=0.f; tu[129]=0.f; tu[130]=0.f; tu[131]=0.f;
    }
    __syncthreads();
    const float w10=W1[0], w11=W1[1], w12=W1[2];
    const float w20=W2[0], w21=W2[1], w22=W2[2];
    const float w23=W2[3], w24=W2[4], w25=W2[5];
    const float b1v=b1[0], b2v=b2[0], b3v=b3[0];
    const int i = 2*lane;
    float c1qa = fmaxf(b1v + w10*q[i]   + w11*q[i+1] + w12*q[i+2], 0.f);
    float c1qb = fmaxf(b1v + w10*q[i+1] + w11*q[i+2] + w12*q[i+3], 0.f);
    float qpa  = w23*q[i]   + w24*q[i+1] + w25*q[i+2];
    float qpb  = w23*q[i+1] + w24*q[i+2] + w25*q[i+3];
    float c1ta = fmaxf(b1v + w10*tu[i]   + w11*tu[i+1] + w12*tu[i+2], 0.f);
    float c1tb = fmaxf(b1v + w10*tu[i+1] + w11*tu[i+2] + w12*tu[i+3], 0.f);
    float c2a  = fmaxf(b2v + w20*tu[i]   + w21*tu[i+1] + w22*tu[i+2] + qpa, 0.f);
    float c2b  = fmaxf(b2v + w20*tu[i+1] + w21*tu[i+2] + w22*tu[i+3] + qpb, 0.f);
    if (lane == 63) { c1qa=0.f; c1qb=0.f; qpa=0.f; qpb=0.f; c1ta=0.f; c1tb=0.f; c2a=0.f; c2b=0.f; }
    c1q[i] = c1qa; c1q[i+1] = c1qb;
    ws[WS_QPRE + b*128 + i]     = qpa;
    ws[WS_QPRE + b*128 + i + 1] = qpb;
    D4[lane] = make_float4(c1ta, c2a, c1tb, c2b);
    __syncthreads();
    float qtv = 0.f;
    if (lane < 63) {
        #pragma unroll
        for (int j = 0; j < 64; ++j) qtv += w3s[64 + j] * c1q[lane + j];
    }
    qt[lane] = qtv;
    ws[WS_QTERM + b*64 + lane] = qtv + b3v;
    __syncthreads();
    float acc0 = b3v + qt[lane];
    float acc1 = 0.f;
    const float2* D2 = (const float2*)D4;
    #pragma unroll
    for (int j = 0; j < 64; ++j) {
        const float2 d = D2[lane + j];
        acc0 = fmaf(w3s[j],       d.x, acc0);
        acc1 = fmaf(w3s[128 + j], d.y, acc1);
    }
    float v = wv * fmaxf(acc0 + acc1, 0.f);
    #pragma unroll
    for (int off = 32; off > 0; off >>= 1) v += __shfl_xor(v, off, 64);
    if (lane == 0) ws[WS_SHIGH + b] = v + be;
}

// ---------------- Kernel C: BARRIER-FREE — 1 wave/block, 64 pairs, full 64 taps per wave ----------------
// Wave owns its pairs end-to-end: private LDS X, B entirely in registers (32 frags),
// epilogue wave-local. Zero __syncthreads -> waves stream independently (TLP latency hiding).
__global__ __launch_bounds__(64, 2) void k_pairs(
    const float* __restrict__ users, const int* __restrict__ uids,
    float* __restrict__ ws, float* __restrict__ out,
    const float* __restrict__ W1, const float* __restrict__ b1,
    const float* __restrict__ W2, const float* __restrict__ b2)
{
    __shared__ __align__(16) unsigned int X[16][132];   // 8448 B private to the wave
    const int lane = threadIdx.x;
    const int bid = blockIdx.x;
    const int b = bid >> 5;            // 32 blocks per batch
    const int cg = bid & 31;
    const int base = b*NN + cg*64;

    // one coalesced uid load; all gates/masks via shuffles
    const int m_lane = uids[base + lane];
    if (__shfl(m_lane, 0, 64) == 0) return;             // prefix property
    const bool a1 = (__shfl(m_lane, 16, 64) != 0);
    const bool a2 = (__shfl(m_lane, 32, 64) != 0);
    const bool a3 = (__shfl(m_lane, 48, 64) != 0);

    const int g = lane >> 4, li = lane & 15;
    const int h = lane >> 5, j = lane & 31;

    // ---- chunk-0 users loads first (critical path) ----
    float4 bufA[8];
    #pragma unroll
    for (int pass = 0; pass < 8; ++pass) {
        const int r = pass*2 + h;
        bufA[pass] = *(const float4*)(users + (size_t)(base + r)*ED + 4*j);
    }

    // ---- full Toeplitz B in registers: 4 n-tiles x 8 k-tiles (L2-resident table) ----
    const __hip_bfloat16* bp = (const __hip_bfloat16*)(ws + WS_BPACK);
    short8v bfr[32];
    #pragma unroll
    for (int nt = 0; nt < 4; ++nt) {
        #pragma unroll
        for (int kt = 0; kt < 8; ++kt) {
            bfr[nt*8 + kt] = *(const short8v*)(bp + (((kt*4 + nt)*64 + lane) << 3));
        }
    }

    // per-lane epilogue constants (taps nt*16 + li)
    float wfl[4], qtl[4];
    #pragma unroll
    for (int nt = 0; nt < 4; ++nt) {
        wfl[nt] = ws[WS_WEFF + nt*16 + li];
        qtl[nt] = ws[WS_QTERM + b*64 + nt*16 + li];
    }
    const float shigh = ws[WS_SHIGH + b], beff = ws[WS_BEFF];
    const float4 qp4 = *(const float4*)&ws[WS_QPRE + b*128 + 4*j];

    const float w10=W1[0], w11=W1[1], w12=W1[2];
    const float w20=W2[0], w21=W2[1], w22=W2[2];
    const float b1v=b1[0], b2v=b2[0];

    float val = 0.f;

#define PREP_C()                                                                    \
    {                                                                               \
        _Pragma("unroll")                                                           \
        for (int pass = 0; pass < 8; ++pass) {                                      \
            const int r = pass*2 + h;                                               \
            const float4 uu = bufA[pass];                                           \
            const float nx = __shfl(uu.x, (lane + 1) & 63, 64);                     \
            const float ny = __shfl(uu.y, (lane + 1) & 63, 64);                     \
            float c10 = fmaxf(b1v + w10*uu.x + w11*uu.y + w12*uu.z, 0.f);           \
            float c11 = fmaxf(b1v + w10*uu.y + w11*uu.z + w12*uu.w, 0.f);           \
            float c12 = fmaxf(b1v + w10*uu.z + w11*uu.w + w12*nx  , 0.f);           \
            float c13 = fmaxf(b1v + w10*uu.w + w11*nx   + w12*ny  , 0.f);           \
            float c20 = fmaxf(b2v + w20*uu.x + w21*uu.y + w22*uu.z + qp4.x, 0.f);   \
            float c21 = fmaxf(b2v + w20*uu.y + w21*uu.z + w22*uu.w + qp4.y, 0.f);   \
            float c22 = fmaxf(b2v + w20*uu.z + w21*uu.w + w22*nx   + qp4.z, 0.f);   \
            float c23 = fmaxf(b2v + w20*uu.w + w21*nx   + w22*ny   + qp4.w, 0.f);   \
            if (j == 31) { c12 = 0.f; c13 = 0.f; c22 = 0.f; c23 = 0.f; }            \
            uint2 v1; v1.x = packbf2(c10, c11); v1.y = packbf2(c12, c13);           \
            uint2 v2; v2.x = packbf2(c20, c21); v2.y = packbf2(c22, c23);           \
            *(uint2*)&X[r][2*j]      = v1;                                          \
            *(uint2*)&X[r][64 + 2*j] = v2;                                          \
        }                                                                           \
    }

#define LOAD_C(COFF)                                                                \
    {                                                                               \
        _Pragma("unroll")                                                           \
        for (int pass = 0; pass < 8; ++pass) {                                      \
            const int r = pass*2 + h;                                               \
            bufA[pass] = *(const float4*)(users + (size_t)(base + (COFF) + r)*ED + 4*j); \
        }                                                                           \
    }

#define GEMM_EP(COFF)                                                               \
    {                                                                               \
        float4v acc0 = {0.f,0.f,0.f,0.f}, acc1 = {0.f,0.f,0.f,0.f};                 \
        float4v acc2 = {0.f,0.f,0.f,0.f}, acc3 = {0.f,0.f,0.f,0.f};                 \
        const char* Xb = (const char*)&X[0][0];                                     \
        _Pragma("unroll")                                                           \
        for (int kt = 0; kt < 8; ++kt) {                                            \
            const short8v a = *(const short8v*)(Xb + li*528 + kt*64 + g*16);        \
            acc0 = __builtin_amdgcn_mfma_f32_16x16x32_bf16(a, bfr[0*8+kt], acc0, 0, 0, 0); \
            acc1 = __builtin_amdgcn_mfma_f32_16x16x32_bf16(a, bfr[1*8+kt], acc1, 0, 0, 0); \
            acc2 = __builtin_amdgcn_mfma_f32_16x16x32_bf16(a, bfr[2*8+kt], acc2, 0, 0, 0); \
            acc3 = __builtin_amdgcn_mfma_f32_16x16x32_bf16(a, bfr[3*8+kt], acc3, 0, 0, 0); \
        }                                                                           \
        _Pragma("unroll")                                                           \
        for (int reg = 0; reg < 4; ++reg) {                                         \
            float v = wfl[0] * fmaxf(acc0[reg] + qtl[0], 0.f)                       \
                    + wfl[1] * fmaxf(acc1[reg] + qtl[1], 0.f)                       \
                    + wfl[2] * fmaxf(acc2[reg] + qtl[2], 0.f)                       \
                    + wfl[3] * fmaxf(acc3[reg] + qtl[3], 0.f);                      \
            v += __shfl_xor(v, 1, 64);                                              \
            v += __shfl_xor(v, 2, 64);                                              \
            v += __shfl_xor(v, 4, 64);                                              \
            v += __shfl_xor(v, 8, 64);                                              \
            const int mk = __shfl(m_lane, (COFF) + g*4 + reg, 64);                  \
            if (li == 0 && mk != 0) {                                               \
                const float d = v + beff - shigh;                                   \
                val += 1.f / (1.f + __expf(-d));                                    \
            }                                                                       \
        }                                                                           \
    }

    // chunk 0
    PREP_C()
    if (a1) LOAD_C(16)
    GEMM_EP(0)
    if (a1) {
        PREP_C()
        if (a2) LOAD_C(32)
        GEMM_EP(16)
        if (a2) {
            PREP_C()
            if (a3) LOAD_C(48)
            GEMM_EP(32)
            if (a3) {
                PREP_C()
                GEMM_EP(48)
            }
        }
    }

    // wave-local final reduce: val lives on lanes 0,16,32,48
    val += __shfl_xor(val, 16, 64);
    val += __shfl_xor(val, 32, 64);
    if (lane == 0) atomicAdd(out, val);   // device-scope

#undef PREP_C
#undef LOAD_C
#undef GEMM_EP
}

extern "C" void kernel_launch(void* const* d_in, const int* in_sizes, int n_in,
                              void* d_out, int out_size, void* d_ws, size_t ws_size,
                              hipStream_t stream)
{
    const float* users    = (const float*)d_in[0];
    const float* top_user = (const float*)d_in[1];
    const float* question = (const float*)d_in[2];
    const int*   uids     = (const int*)d_in[3];
    const float* W1  = (const float*)d_in[4];
    const float* b1  = (const float*)d_in[5];
    const float* W2  = (const float*)d_in[6];
    const float* b2  = (const float*)d_in[7];
    const float* W3  = (const float*)d_in[8];
    const float* b3  = (const float*)d_in[9];
    const float* fw1 = (const float*)d_in[10];
    const float* fb1 = (const float*)d_in[11];
    const float* fw2 = (const float*)d_in[12];
    const float* fb2 = (const float*)d_in[13];
    const float* fw3 = (const float*)d_in[14];
    const float* fb3 = (const float*)d_in[15];
    float* ws  = (float*)d_ws;
    float* out = (float*)d_out;

    hipLaunchKernelGGL(k_prep, dim3(NB + 8), dim3(64), 0, stream,
                       top_user, question, W1, b1, W2, b2, W3, b3,
                       fw1, fb1, fw2, fb2, fw3, fb3, ws, out);
    hipLaunchKernelGGL(k_pairs, dim3(GRID_P), dim3(64), 0, stream,
                       users, uids, ws, out, W1, b1, W2, b2);
}

// Round 16
// 28.082 us; speedup vs baseline: 1.2548x; 1.2548x over previous
//
#include <hip/hip_runtime.h>
#include <hip/hip_bf16.h>

typedef __attribute__((ext_vector_type(8))) short short8v;
typedef __attribute__((ext_vector_type(4))) float float4v;

// Problem constants
#define NB 64
#define NN 2048
#define ED 128
#define GRID_P 512            // k_pairs blocks; each takes compacted chunks bid, bid+512, ...

// workspace layout (float offsets)
#define WS_WEFF  0                  // 64 (weff[63], [63]=0)
#define WS_BEFF  64                 // 1
#define WS_SHIGH 128                // 64
#define WS_QTERM 192                // 64*64  (qterm + b3 folded)
#define WS_QPRE  (192+4096)         // 64*128
#define WS_BPACK (192+4096+8192)    // bf16[16384] = 32768 B = 8192 floats  (NOT 4096 — r15 bug)
#define WS_QCNT  (WS_BPACK+8192)    // 8 ints (per-segment active counts)
#define WS_QLIST (WS_QCNT+8)        // 2048 ints (compacted chunk ids, 8 segments of <=256)

static __device__ __forceinline__ unsigned int packbf2(float a, float b) {
    __hip_bfloat162 h = __float22bfloat162_rn(make_float2(a, b));
    return *(unsigned int*)&h;
}

// ---------------- Kernel P ----------------
// blocks 0..NB-1: per-batch precompute. NB..NB+7: bpack slice (kt==0 also weff/beff/out-reset).
// NB+8..NB+15: scan 256 chunks each -> compacted active-chunk list (ballot compaction, no atomics).
__global__ __launch_bounds__(64) void k_prep(
    const float* __restrict__ top_user, const float* __restrict__ question,
    const float* __restrict__ W1, const float* __restrict__ b1,
    const float* __restrict__ W2, const float* __restrict__ b2,
    const float* __restrict__ W3, const float* __restrict__ b3,
    const float* __restrict__ fw1, const float* __restrict__ fb1,
    const float* __restrict__ fw2, const float* __restrict__ fb2,
    const float* __restrict__ fw3, const float* __restrict__ fb3,
    const int* __restrict__ uids,
    float* __restrict__ ws, float* __restrict__ out)
{
    const int lane = threadIdx.x;
    const int blk = blockIdx.x;

    if (blk >= NB + 8) {
        // ---- scan segment s: chunks s*256 .. s*256+255 ----
        const int s = blk - NB - 8;
        int* qcnti  = (int*)(ws + WS_QCNT);
        int* qlisti = (int*)(ws + WS_QLIST);
        int running = 0;
        #pragma unroll
        for (int it = 0; it < 4; ++it) {
            const int c = s*256 + it*64 + lane;
            const int act = (uids[c * 64] != 0) ? 1 : 0;
            const unsigned long long mask = __ballot(act);
            const int pos = running + __popcll(mask & ((1ull << lane) - 1ull));
            if (act) qlisti[s*256 + pos] = c;
            running += (int)__popcll(mask);
        }
        if (lane == 0) qcnti[s] = running;
        return;
    }

    __shared__ float g[16];
    __shared__ float w3s[192];
    w3s[lane] = W3[lane];
    w3s[64 + lane] = W3[64 + lane];
    w3s[128 + lane] = W3[128 + lane];
    if (lane < 16) {
        float s = 0.f;
        #pragma unroll
        for (int i = 0; i < 16; ++i) s += fw3[i] * fw2[i*16 + lane];
        g[lane] = s;
    }
    __syncthreads();

    if (blk >= NB) {
        const int kt = blk - NB;
        if (kt == 0) {
            if (lane == 0) out[0] = 0.f;
            float wv = 0.f;
            if (lane < 63) {
                #pragma unroll
                for (int k = 0; k < 16; ++k) wv += g[k] * fw1[k*63 + lane];
            }
            ws[WS_WEFF + lane] = wv;
            if (lane == 0) {
                float be = fb3[0];
                #pragma unroll
                for (int i = 0; i < 16; ++i) be += fw3[i] * fb2[i];
                #pragma unroll
                for (int k = 0; k < 16; ++k) be += g[k] * fb1[k];
                ws[WS_BEFF] = be;
            }
        }
        __hip_bfloat16* bp = (__hip_bfloat16*)(ws + WS_BPACK);
        const int g8 = (lane >> 4) * 8, li = lane & 15;
        #pragma unroll
        for (int nt = 0; nt < 4; ++nt) {
            const int tt = nt*16 + li;
            #pragma unroll
            for (int idx = 0; idx < 8; ++idx) {
                const int k = kt*32 + g8 + idx;
                const int j = k - tt;
                const int k2 = k - 128, j2 = k2 - tt;
                const bool v0 = (tt < 63) && (k < 126) && (j >= 0) && (j < 64);
                const bool v2 = (tt < 63) && (k2 >= 0) && (k2 < 126) && (j2 >= 0) && (j2 < 64);
                float v = (v0 ? w3s[j & 63] : 0.f) + (v2 ? w3s[128 + (j2 & 63)] : 0.f);
                bp[((kt*4 + nt)*64 + lane)*8 + idx] = __float2bfloat16(v);
            }
        }
        return;
    }

    // per-batch precompute
    float wv = 0.f;
    if (lane < 63) {
        #pragma unroll
        for (int k = 0; k < 16; ++k) wv += g[k] * fw1[k*63 + lane];
    }
    float be = fb3[0];
    #pragma unroll
    for (int i = 0; i < 16; ++i) be += fw3[i] * fb2[i];
    #pragma unroll
    for (int k = 0; k < 16; ++k) be += g[k] * fb1[k];

    __shared__ float q[132], tu[132], c1q[128], qt[64];
    __shared__ float4 D4[64];
    const int b = blk;
    ((float2*)q)[lane]  = ((const float2*)(question + b*ED))[lane];
    ((float2*)tu)[lane] = ((const float2*)(top_user + b*ED))[lane];
    if (lane == 63) {
        q[128]=0.f; q[129]=0.f; q[130]=0.f; q[131]=0.f;
        tu[128]=0.f; tu[129]=0.f; tu[130]=0.f; tu[131]=0.f;
    }
    __syncthreads();
    const float w10=W1[0], w11=W1[1], w12=W1[2];
    const float w20=W2[0], w21=W2[1], w22=W2[2];
    const float w23=W2[3], w24=W2[4], w25=W2[5];
    const float b1v=b1[0], b2v=b2[0], b3v=b3[0];
    const int i = 2*lane;
    float c1qa = fmaxf(b1v + w10*q[i]   + w11*q[i+1] + w12*q[i+2], 0.f);
    float c1qb = fmaxf(b1v + w10*q[i+1] + w11*q[i+2] + w12*q[i+3], 0.f);
    float qpa  = w23*q[i]   + w24*q[i+1] + w25*q[i+2];
    float qpb  = w23*q[i+1] + w24*q[i+2] + w25*q[i+3];
    float c1ta = fmaxf(b1v + w10*tu[i]   + w11*tu[i+1] + w12*tu[i+2], 0.f);
    float c1tb = fmaxf(b1v + w10*tu[i+1] + w11*tu[i+2] + w12*tu[i+3], 0.f);
    float c2a  = fmaxf(b2v + w20*tu[i]   + w21*tu[i+1] + w22*tu[i+2] + qpa, 0.f);
    float c2b  = fmaxf(b2v + w20*tu[i+1] + w21*tu[i+2] + w22*tu[i+3] + qpb, 0.f);
    if (lane == 63) { c1qa=0.f; c1qb=0.f; qpa=0.f; qpb=0.f; c1ta=0.f; c1tb=0.f; c2a=0.f; c2b=0.f; }
    c1q[i] = c1qa; c1q[i+1] = c1qb;
    ws[WS_QPRE + b*128 + i]     = qpa;
    ws[WS_QPRE + b*128 + i + 1] = qpb;
    D4[lane] = make_float4(c1ta, c2a, c1tb, c2b);
    __syncthreads();
    float qtv = 0.f;
    if (lane < 63) {
        #pragma unroll
        for (int j = 0; j < 64; ++j) qtv += w3s[64 + j] * c1q[lane + j];
    }
    qt[lane] = qtv;
    ws[WS_QTERM + b*64 + lane] = qtv + b3v;
    __syncthreads();
    float acc0 = b3v + qt[lane];
    float acc1 = 0.f;
    const float2* D2 = (const float2*)D4;
    #pragma unroll
    for (int j = 0; j < 64; ++j) {
        const float2 d = D2[lane + j];
        acc0 = fmaf(w3s[j],       d.x, acc0);
        acc1 = fmaf(w3s[128 + j], d.y, acc1);
    }
    float v = wv * fmaxf(acc0 + acc1, 0.f);
    #pragma unroll
    for (int off = 32; off > 0; off >>= 1) v += __shfl_xor(v, off, 64);
    if (lane == 0) ws[WS_SHIGH + b] = v + be;
}

// ---------------- Kernel C: balanced compacted chunks, r12 pipeline ----------------
// NOTE: no min-waves launch-bounds arg (VGPR cap kills prefetch — r4/r8/r9).
__global__ __launch_bounds__(256) void k_pairs(
    const float* __restrict__ users, const int* __restrict__ uids,
    float* __restrict__ ws, float* __restrict__ out,
    const float* __restrict__ W1, const float* __restrict__ b1,
    const float* __restrict__ W2, const float* __restrict__ b2)
{
    __shared__ __align__(16) unsigned int X2[2][64][132];   // 2 x 33792 B
    __shared__ float pscore[2][2][64];
    const int tid = threadIdx.x;
    const int w = tid >> 6, lane = tid & 63;
    const int bid = blockIdx.x;

    const int gfr = lane >> 4, li = lane & 15;
    const int nhalf = w >> 1;
    const int mbase = (w & 1) * 32;
    const int h = lane >> 5, j = lane & 31;
    const int r0 = w * 16;

    // ---- resolve my chunks from the compacted list (uniform scalar loads) ----
    const int* qcnti  = (const int*)(ws + WS_QCNT);
    const int* qlisti = (const int*)(ws + WS_QLIST);
    int pref[9]; pref[0] = 0;
    #pragma unroll
    for (int s = 0; s < 8; ++s) pref[s+1] = pref[s] + qcnti[s];
    const int total = pref[8];
    int myc[4];
    #pragma unroll
    for (int k = 0; k < 4; ++k) {
        const int vid = bid + k*GRID_P;
        int c = -1;
        if (vid < total) {
            int seg = 0;
            #pragma unroll
            for (int s = 1; s < 8; ++s) seg += (vid >= pref[s]) ? 1 : 0;
            c = qlisti[seg*256 + (vid - pref[seg])];
        }
        myc[k] = c;
    }
    const int c0 = myc[0], c1 = myc[1], c2 = myc[2], c3 = myc[3];
    if (c0 < 0) return;

    const int pa0 = c0*64;
    const int pa1 = (c1 >= 0) ? c1*64 : 0;
    const int pa2 = (c2 >= 0) ? c2*64 : 0;
    const int pa3 = (c3 >= 0) ? c3*64 : 0;

    // ---- chunk-0/1 users loads first (critical path) ----
    float4 bufA[8], bufB[8];
    #pragma unroll
    for (int pass = 0; pass < 8; ++pass) {
        const int r = r0 + pass*2 + h;
        bufA[pass] = *(const float4*)(users + (size_t)(pa0 + r)*ED + 4*j);
    }
    if (c1 >= 0) {
        #pragma unroll
        for (int pass = 0; pass < 8; ++pass) {
            const int r = r0 + pass*2 + h;
            bufB[pass] = *(const float4*)(users + (size_t)(pa1 + r)*ED + 4*j);
        }
    }

    // B fragments (32KB, L2/L3-resident)
    const __hip_bfloat16* bp = (const __hip_bfloat16*)(ws + WS_BPACK);
    short8v bfr0[8], bfr1[8];
    #pragma unroll
    for (int kt = 0; kt < 8; ++kt) {
        bfr0[kt] = *(const short8v*)(bp + (((kt*4 + nhalf*2 + 0)*64 + lane) << 3));
        bfr1[kt] = *(const short8v*)(bp + (((kt*4 + nhalf*2 + 1)*64 + lane) << 3));
    }

    const int t0 = nhalf*32 + li, t1 = t0 + 16;
    const float wf0 = ws[WS_WEFF + t0], wf1 = ws[WS_WEFF + t1];
    const float beff = ws[WS_BEFF];

    // per-chunk batch constants + masks
    const int b0 = c0 >> 5;
    const float qta0 = ws[WS_QTERM + b0*64 + t0], qtb0 = ws[WS_QTERM + b0*64 + t1];
    const float sh0 = ws[WS_SHIGH + b0];
    const float4 qp0 = *(const float4*)&ws[WS_QPRE + b0*128 + 4*j];
    const int m0 = (w == 0) ? uids[pa0 + lane] : 1;

    const int b1i = (c1 >= 0) ? (c1 >> 5) : 0;
    const float qta1 = ws[WS_QTERM + b1i*64 + t0], qtb1 = ws[WS_QTERM + b1i*64 + t1];
    const float sh1 = ws[WS_SHIGH + b1i];
    const float4 qp1 = *(const float4*)&ws[WS_QPRE + b1i*128 + 4*j];
    const int m1 = (w == 0 && c1 >= 0) ? uids[pa1 + lane] : 1;

    const int b2i = (c2 >= 0) ? (c2 >> 5) : 0;
    const float qta2 = ws[WS_QTERM + b2i*64 + t0], qtb2 = ws[WS_QTERM + b2i*64 + t1];
    const float sh2 = ws[WS_SHIGH + b2i];
    const float4 qp2 = *(const float4*)&ws[WS_QPRE + b2i*128 + 4*j];
    const int m2 = (w == 0 && c2 >= 0) ? uids[pa2 + lane] : 1;

    const int b3i = (c3 >= 0) ? (c3 >> 5) : 0;
    const float qta3 = ws[WS_QTERM + b3i*64 + t0], qtb3 = ws[WS_QTERM + b3i*64 + t1];
    const float sh3 = ws[WS_SHIGH + b3i];
    const float4 qp3 = *(const float4*)&ws[WS_QPRE + b3i*128 + 4*j];
    const int m3 = (w == 0 && c3 >= 0) ? uids[pa3 + lane] : 1;

    const float w10=W1[0], w11=W1[1], w12=W1[2];
    const float w20=W2[0], w21=W2[1], w22=W2[2];
    const float b1v=b1[0], b2v=b2[0];

#define PREP_BODY(BUF, XB, QP)                                                      \
    {                                                                               \
        _Pragma("unroll")                                                           \
        for (int pass = 0; pass < 8; ++pass) {                                      \
            const int r = r0 + pass*2 + h;                                          \
            const float4 uu = BUF[pass];                                            \
            const float nx = __shfl(uu.x, (lane + 1) & 63, 64);                     \
            const float ny = __shfl(uu.y, (lane + 1) & 63, 64);                     \
            float c10 = fmaxf(b1v + w10*uu.x + w11*uu.y + w12*uu.z, 0.f);           \
            float c11 = fmaxf(b1v + w10*uu.y + w11*uu.z + w12*uu.w, 0.f);           \
            float c12 = fmaxf(b1v + w10*uu.z + w11*uu.w + w12*nx  , 0.f);           \
            float c13 = fmaxf(b1v + w10*uu.w + w11*nx   + w12*ny  , 0.f);           \
            float c20 = fmaxf(b2v + w20*uu.x + w21*uu.y + w22*uu.z + QP.x, 0.f);    \
            float c21 = fmaxf(b2v + w20*uu.y + w21*uu.z + w22*uu.w + QP.y, 0.f);    \
            float c22 = fmaxf(b2v + w20*uu.z + w21*uu.w + w22*nx   + QP.z, 0.f);    \
            float c23 = fmaxf(b2v + w20*uu.w + w21*nx   + w22*ny   + QP.w, 0.f);    \
            if (j == 31) { c12 = 0.f; c13 = 0.f; c22 = 0.f; c23 = 0.f; }            \
            uint2 v1; v1.x = packbf2(c10, c11); v1.y = packbf2(c12, c13);           \
            uint2 v2; v2.x = packbf2(c20, c21); v2.y = packbf2(c22, c23);           \
            *(uint2*)&X2[XB][r][2*j]      = v1;                                     \
            *(uint2*)&X2[XB][r][64 + 2*j] = v2;                                     \
        }                                                                           \
    }

#define LOAD_INTO(BUF, PA)                                                          \
    {                                                                               \
        _Pragma("unroll")                                                           \
        for (int pass = 0; pass < 8; ++pass) {                                      \
            const int r = r0 + pass*2 + h;                                          \
            BUF[pass] = *(const float4*)(users + (size_t)((PA) + r)*ED + 4*j);      \
        }                                                                           \
    }

    auto gemm = [&](int xb, int psl, float qta, float qtb) {
        float4v acc00 = {0.f,0.f,0.f,0.f}, acc01 = {0.f,0.f,0.f,0.f};
        float4v acc10 = {0.f,0.f,0.f,0.f}, acc11 = {0.f,0.f,0.f,0.f};
        const char* Xb = (const char*)&X2[xb][0][0];
        #pragma unroll
        for (int kt = 0; kt < 8; ++kt) {
            const short8v aa0 = *(const short8v*)(Xb + (mbase + li)*528      + kt*64 + gfr*16);
            const short8v aa1 = *(const short8v*)(Xb + (mbase + 16 + li)*528 + kt*64 + gfr*16);
            acc00 = __builtin_amdgcn_mfma_f32_16x16x32_bf16(aa0, bfr0[kt], acc00, 0, 0, 0);
            acc01 = __builtin_amdgcn_mfma_f32_16x16x32_bf16(aa0, bfr1[kt], acc01, 0, 0, 0);
            acc10 = __builtin_amdgcn_mfma_f32_16x16x32_bf16(aa1, bfr0[kt], acc10, 0, 0, 0);
            acc11 = __builtin_amdgcn_mfma_f32_16x16x32_bf16(aa1, bfr1[kt], acc11, 0, 0, 0);
        }
        #pragma unroll
        for (int mi = 0; mi < 2; ++mi) {
            #pragma unroll
            for (int reg = 0; reg < 4; ++reg) {
                const float a0v = mi ? acc10[reg] : acc00[reg];
                const float a1v = mi ? acc11[reg] : acc01[reg];
                float v = wf0 * fmaxf(a0v + qta, 0.f) + wf1 * fmaxf(a1v + qtb, 0.f);
                v += __shfl_xor(v, 1, 64);
                v += __shfl_xor(v, 2, 64);
                v += __shfl_xor(v, 4, 64);
                v += __shfl_xor(v, 8, 64);
                if (li == 0) pscore[psl][nhalf][mbase + mi*16 + gfr*4 + reg] = v;
            }
        }
    };

    float val = 0.f;
    auto sig = [&](int psl, int m, float sh) {
        if (w == 0) {
            const float d = pscore[psl][0][lane] + pscore[psl][1][lane] + beff - sh;
            if (m != 0) val += 1.f / (1.f + __expf(-d));
        }
    };

    // ---- pipeline over up to 4 balanced chunks ----
    PREP_BODY(bufA, 0, qp0)
    __syncthreads();                       // X0 ready

    if (c2 >= 0) LOAD_INTO(bufA, pa2)
    gemm(0, 0, qta0, qtb0);
    if (c1 >= 0) PREP_BODY(bufB, 1, qp1)
    __syncthreads();                       // pscore0(c0), X1 ready

    sig(0, m0, sh0);
    if (c1 >= 0) {
        if (c3 >= 0) LOAD_INTO(bufB, pa3)
        gemm(1, 1, qta1, qtb1);
        if (c2 >= 0) PREP_BODY(bufA, 0, qp2)
        __syncthreads();                   // pscore1(c1), X0(c2) ready

        sig(1, m1, sh1);
        if (c2 >= 0) {
            gemm(0, 0, qta2, qtb2);
            if (c3 >= 0) PREP_BODY(bufB, 1, qp3)
            __syncthreads();               // pscore0(c2), X1(c3) ready

            sig(0, m2, sh2);
            if (c3 >= 0) {
                gemm(1, 1, qta3, qtb3);
                __syncthreads();           // pscore1(c3) ready
                sig(1, m3, sh3);
            }
        }
    }

    if (w == 0) {
        #pragma unroll
        for (int off = 32; off > 0; off >>= 1) val += __shfl_xor(val, off, 64);
        if (lane == 0) atomicAdd(out, val);   // device-scope
    }
#undef PREP_BODY
#undef LOAD_INTO
}

extern "C" void kernel_launch(void* const* d_in, const int* in_sizes, int n_in,
                              void* d_out, int out_size, void* d_ws, size_t ws_size,
                              hipStream_t stream)
{
    const float* users    = (const float*)d_in[0];
    const float* top_user = (const float*)d_in[1];
    const float* question = (const float*)d_in[2];
    const int*   uids     = (const int*)d_in[3];
    const float* W1  = (const float*)d_in[4];
    const float* b1  = (const float*)d_in[5];
    const float* W2  = (const float*)d_in[6];
    const float* b2  = (const float*)d_in[7];
    const float* W3  = (const float*)d_in[8];
    const float* b3  = (const float*)d_in[9];
    const float* fw1 = (const float*)d_in[10];
    const float* fb1 = (const float*)d_in[11];
    const float* fw2 = (const float*)d_in[12];
    const float* fb2 = (const float*)d_in[13];
    const float* fw3 = (const float*)d_in[14];
    const float* fb3 = (const float*)d_in[15];
    float* ws  = (float*)d_ws;
    float* out = (float*)d_out;

    hipLaunchKernelGGL(k_prep, dim3(NB + 16), dim3(64), 0, stream,
                       top_user, question, W1, b1, W2, b2, W3, b3,
                       fw1, fb1, fw2, fb2, fw3, fb3, uids, ws, out);
    hipLaunchKernelGGL(k_pairs, dim3(GRID_P), dim3(256), 0, stream,
                       users, uids, ws, out, W1, b1, W2, b2);
}